// Round 2
// baseline (86.897 us; speedup 1.0000x reference)
//
#include <hip/hip_runtime.h>

#define NUM_IND   1000

// Native vector type so __builtin_nontemporal_{load,store} accepts it.
typedef float f4 __attribute__((ext_vector_type(4)));

// Kernel 1: collapse the whole per-industry pipeline into a 1000x32 table.
// table[t] = relu(vars[t] @ W1 + b1) @ W2 + b2 + 0.1*emb[t]
__global__ void build_table_kernel(const float* __restrict__ vars,  // [1000,8]
                                   const float* __restrict__ W1,    // [8,16]
                                   const float* __restrict__ b1,    // [16]
                                   const float* __restrict__ W2,    // [16,32]
                                   const float* __restrict__ b2,    // [32]
                                   const float* __restrict__ emb,   // [1000,32]
                                   float* __restrict__ table)       // [1000,32]
{
    int t = blockIdx.x * blockDim.x + threadIdx.x;
    if (t >= NUM_IND) return;

    float v[8];
#pragma unroll
    for (int k = 0; k < 8; ++k) v[k] = vars[t * 8 + k];

    float h[16];
#pragma unroll
    for (int j = 0; j < 16; ++j) {
        float acc = b1[j];
#pragma unroll
        for (int k = 0; k < 8; ++k) acc = fmaf(v[k], W1[k * 16 + j], acc);
        h[j] = fmaxf(acc, 0.0f);
    }

#pragma unroll
    for (int j = 0; j < 32; ++j) {
        float acc = b2[j];
#pragma unroll
        for (int k = 0; k < 16; ++k) acc = fmaf(h[k], W2[k * 32 + j], acc);
        table[t * 32 + j] = acc + 0.1f * emb[t * 32 + j];
    }
}

// Kernel 2: pure gather, 4-way unrolled grid-stride for MLP (4 independent
// idx loads -> 4 independent table loads -> 4 nt-stores per body).
// Thread-per-f4: g>>3 = example, g&7 = 16B chunk; a wave's 64 lanes write one
// contiguous 1 KB segment. Output stores are NON-TEMPORAL (write-once stream
// must not evict the L2-resident 128 KB table). idx loads also nt (read-once).
__global__ __launch_bounds__(256) void gather_kernel(
    const int* __restrict__ idx,
    const f4*  __restrict__ table4,  // [1000*8]
    f4*        __restrict__ out4,    // [B*8]
    int total4)                       // B*8
{
    const int stride = gridDim.x * blockDim.x;
    int g = blockIdx.x * blockDim.x + threadIdx.x;

    for (; g + 3 * stride < total4; g += 4 * stride) {
        const int g0 = g;
        const int g1 = g + stride;
        const int g2 = g + 2 * stride;
        const int g3 = g + 3 * stride;
        // 4 independent idx loads (nt: read-once stream, don't cache in L2)
        const int i0 = __builtin_nontemporal_load(&idx[g0 >> 3]);
        const int i1 = __builtin_nontemporal_load(&idx[g1 >> 3]);
        const int i2 = __builtin_nontemporal_load(&idx[g2 >> 3]);
        const int i3 = __builtin_nontemporal_load(&idx[g3 >> 3]);
        // 4 independent table reads (cached: 128 KB table should stay in L2)
        const f4 t0 = table4[i0 * 8 + (g0 & 7)];
        const f4 t1 = table4[i1 * 8 + (g1 & 7)];
        const f4 t2 = table4[i2 * 8 + (g2 & 7)];
        const f4 t3 = table4[i3 * 8 + (g3 & 7)];
        // 4 non-temporal stores (write-once output must not thrash L2)
        __builtin_nontemporal_store(t0, &out4[g0]);
        __builtin_nontemporal_store(t1, &out4[g1]);
        __builtin_nontemporal_store(t2, &out4[g2]);
        __builtin_nontemporal_store(t3, &out4[g3]);
    }
    for (; g < stride * ((total4 + stride - 1) / stride); g += stride) {
        if (g < total4) {
            const int id = __builtin_nontemporal_load(&idx[g >> 3]);
            const f4 t = table4[id * 8 + (g & 7)];
            __builtin_nontemporal_store(t, &out4[g]);
        }
    }
}

extern "C" void kernel_launch(void* const* d_in, const int* in_sizes, int n_in,
                              void* d_out, int out_size, void* d_ws, size_t ws_size,
                              hipStream_t stream) {
    const int*   idx  = (const int*)  d_in[0];  // [B] int32
    const float* vars = (const float*)d_in[1];  // [1000,8]
    const float* W1   = (const float*)d_in[2];  // [8,16]
    const float* b1   = (const float*)d_in[3];  // [16]
    const float* W2   = (const float*)d_in[4];  // [16,32]
    const float* b2   = (const float*)d_in[5];  // [32]
    const float* emb  = (const float*)d_in[6];  // [1000,32]

    float* table = (float*)d_ws;                // 1000*32*4 = 128 KB
    float* out   = (float*)d_out;               // [B,32]

    const int B = in_sizes[0];

    // Build the 1000x32 table (4 blocks x 256 = 1024 threads >= 1000).
    build_table_kernel<<<4, 256, 0, stream>>>(vars, W1, b1, W2, b2, emb, table);

    // Gather: B*8 f4 elements, 4x-unrolled grid-stride over 2048 blocks.
    const int total4 = B * 8;
    gather_kernel<<<2048, 256, 0, stream>>>(idx, (const f4*)table,
                                            (f4*)out, total4);
}

// Round 3
// 70.507 us; speedup vs baseline: 1.2325x; 1.2325x over previous
//
#include <hip/hip_runtime.h>

#define NUM_IND   1000

typedef float f4 __attribute__((ext_vector_type(4)));

// Kernel 1: collapse the whole per-industry pipeline into a 1000x32 table.
// table[t] = relu(vars[t] @ W1 + b1) @ W2 + b2 + 0.1*emb[t]
__global__ void build_table_kernel(const float* __restrict__ vars,  // [1000,8]
                                   const float* __restrict__ W1,    // [8,16]
                                   const float* __restrict__ b1,    // [16]
                                   const float* __restrict__ W2,    // [16,32]
                                   const float* __restrict__ b2,    // [32]
                                   const float* __restrict__ emb,   // [1000,32]
                                   float* __restrict__ table)       // [1000,32]
{
    int t = blockIdx.x * blockDim.x + threadIdx.x;
    if (t >= NUM_IND) return;

    float v[8];
#pragma unroll
    for (int k = 0; k < 8; ++k) v[k] = vars[t * 8 + k];

    float h[16];
#pragma unroll
    for (int j = 0; j < 16; ++j) {
        float acc = b1[j];
#pragma unroll
        for (int k = 0; k < 8; ++k) acc = fmaf(v[k], W1[k * 16 + j], acc);
        h[j] = fmaxf(acc, 0.0f);
    }

#pragma unroll
    for (int j = 0; j < 32; ++j) {
        float acc = b2[j];
#pragma unroll
        for (int k = 0; k < 16; ++k) acc = fmaf(h[k], W2[k * 32 + j], acc);
        table[t * 32 + j] = acc + 0.1f * emb[t * 32 + j];
    }
}

// Kernel 2: pure gather, ONE f4 per thread, exact grid (no loop).
// g>>3 = example, g&7 = 16B chunk; a wave's 64 lanes write one contiguous
// 1 KB segment (fully coalesced); 8 lanes share one idx (cache broadcast);
// 128 KB table stays L2-hot. Latency hiding = pure TLP (fill-kernel regime):
// no inter-iteration dependency chains, 2048 threads/CU in flight.
__global__ __launch_bounds__(256) void gather_kernel(
    const int* __restrict__ idx,
    const f4*  __restrict__ table4,  // [1000*8]
    f4*        __restrict__ out4,    // [B*8]
    int total4)                       // B*8
{
    const int g = blockIdx.x * blockDim.x + threadIdx.x;
    if (g >= total4) return;
    const int id = idx[g >> 3];
    out4[g] = table4[id * 8 + (g & 7)];
}

extern "C" void kernel_launch(void* const* d_in, const int* in_sizes, int n_in,
                              void* d_out, int out_size, void* d_ws, size_t ws_size,
                              hipStream_t stream) {
    const int*   idx  = (const int*)  d_in[0];  // [B] int32
    const float* vars = (const float*)d_in[1];  // [1000,8]
    const float* W1   = (const float*)d_in[2];  // [8,16]
    const float* b1   = (const float*)d_in[3];  // [16]
    const float* W2   = (const float*)d_in[4];  // [16,32]
    const float* b2   = (const float*)d_in[5];  // [32]
    const float* emb  = (const float*)d_in[6];  // [1000,32]

    float* table = (float*)d_ws;                // 1000*32*4 = 128 KB
    float* out   = (float*)d_out;               // [B,32]

    const int B = in_sizes[0];

    // Build the 1000x32 table (4 blocks x 256 = 1024 threads >= 1000).
    build_table_kernel<<<4, 256, 0, stream>>>(vars, W1, b1, W2, b2, emb, table);

    // Gather: B*8 f4 elements, one per thread, exact grid.
    const int total4 = B * 8;
    const int blocks = (total4 + 255) / 256;
    gather_kernel<<<blocks, 256, 0, stream>>>(idx, (const f4*)table,
                                              (f4*)out, total4);
}